// Round 6
// baseline (2140.588 us; speedup 1.0000x reference)
//
#include <hip/hip_runtime.h>
#include <math.h>

#define UNITS 1024
#define FEAT 128
#define TSEQ 48
#define BATCH 2048
#define OUT_STEPS 24
#define KTOT 1152            // FEAT + UNITS
#define N4 4096

typedef unsigned short ushort;
typedef __attribute__((ext_vector_type(8))) short bf16x8;
typedef __attribute__((ext_vector_type(4))) float f32x4;

__device__ __forceinline__ ushort f2bf(float f) {
  unsigned u = __float_as_uint(f);
  unsigned r = (u + 0x7FFF + ((u >> 16) & 1)) >> 16;
  return (ushort)r;
}
__device__ __forceinline__ float sigm(float x) { return 1.0f / (1.0f + __expf(-x)); }
__device__ __forceinline__ float tanh_f(float x) { return 1.0f - 2.0f / (1.0f + __expf(2.0f * x)); }

__device__ __forceinline__ void gload_lds16(const void* g, void* l) {
  __builtin_amdgcn_global_load_lds(
      (const __attribute__((address_space(1))) unsigned int*)g,
      (__attribute__((address_space(3))) unsigned int*)l, 16, 0, 0);
}

// ---------------- prep kernels ----------------

// inputs [B][T][F] fp32 -> Xb [T][B][F] bf16
__global__ __launch_bounds__(256)
void convert_inputs_kernel(const float* __restrict__ in, ushort* __restrict__ Xb) {
  const int o4 = (blockIdx.x * 256 + threadIdx.x) * 4;
  const int t = o4 >> 18;
  const int b = (o4 >> 7) & 2047;
  const int f = o4 & 127;
  const float4 v = *reinterpret_cast<const float4*>(&in[(size_t)(b * TSEQ + t) * FEAT + f]);
  union { ushort u[4]; unsigned long long ll; } w;
  w.u[0] = f2bf(v.x); w.u[1] = f2bf(v.y); w.u[2] = f2bf(v.z); w.u[3] = f2bf(v.w);
  *reinterpret_cast<unsigned long long*>(&Xb[o4]) = w.ll;
}

// Build WpF: warmup weights in MFMA-fragment order.
// Fragment (cf, kc): 64 lanes x 8 bf16. lane = kgq*16 + u16loc; np = cf*16 + u16loc;
// k = kc*32 + kgq*8 + e. np = gate-permuted col: np = ugrp*64 + gate*16 + u16,
// source col = gate*1024 + ugrp*16 + u16. Row k<128 -> kernel, else recurrent.
__global__ __launch_bounds__(256)
void prep_wF_kernel(const float* __restrict__ kW, const float* __restrict__ rW,
                    ushort* __restrict__ WpF) {
  const int g = blockIdx.x * 256 + threadIdx.x;   // (cf*36 + kc)*64 + lane
  const int lane = g & 63;
  const int kc = (g >> 6) % 36;
  const int cf = g / 2304;                         // 36*64
  const int np = cf * 16 + (lane & 15);
  const int kbase = kc * 32 + (lane >> 4) * 8;
  const int u16 = np & 15, gg = (np >> 4) & 3, ugrp = np >> 6;
  const int nsrc = gg * 1024 + ugrp * 16 + u16;
  ushort v[8];
#pragma unroll
  for (int e = 0; e < 8; ++e) {
    const int k = kbase + e;
    const float f = (k < FEAT) ? kW[(size_t)k * N4 + nsrc] : rW[(size_t)(k - FEAT) * N4 + nsrc];
    v[e] = f2bf(f);
  }
  *reinterpret_cast<bf16x8*>(&WpF[(size_t)g * 8]) = *reinterpret_cast<bf16x8*>(v);
}

// dense_w [1024][128] fp32 -> Wdt [128][1024] bf16 (transposed)
__global__ __launch_bounds__(256)
void prep_wd_kernel(const float* __restrict__ dw, ushort* __restrict__ Wdt) {
  const int o = blockIdx.x * 256 + threadIdx.x;
  const int n = o >> 10, k = o & 1023;
  Wdt[o] = f2bf(dw[(size_t)k * FEAT + n]);
}

// b2[n] = bias[n] + sum_f db[f] * W[f][n]   (original gate order)
__global__ __launch_bounds__(256)
void prep_b2_kernel(const float* __restrict__ bias, const float* __restrict__ db,
                    const float* __restrict__ W, float* __restrict__ b2) {
  const int n = blockIdx.x * 256 + threadIdx.x;
  float s = bias[n];
#pragma unroll 8
  for (int f = 0; f < FEAT; ++f) s += db[f] * W[(size_t)f * N4 + n];
  b2[n] = s;
}

// U' = Wd@W + U -> Wp2F in fragment order (NKS=32).
__global__ __launch_bounds__(256)
void prep_u_kernel(const float* __restrict__ dw,   // [1024][128]
                   const float* __restrict__ W,    // [128][4096]
                   const float* __restrict__ rW,   // [1024][4096]
                   ushort* __restrict__ Wp2F) {
  __shared__ float sWd[64][132];   // [k_local][f]
  __shared__ float sW[128][68];    // [f][n'_local]
  const int tid = threadIdx.x;
  const int ugrp = blockIdx.x;
  const int k0 = blockIdx.y * 64;
  const int n0 = ugrp * 64;

#pragma unroll
  for (int p = 0; p < 8; ++p) {
    const int li = p * 256 + tid;
    const int kk = li >> 5, f4 = (li & 31) * 4;
    *reinterpret_cast<float4*>(&sWd[kk][f4]) =
        *reinterpret_cast<const float4*>(&dw[(size_t)(k0 + kk) * FEAT + f4]);
  }
#pragma unroll
  for (int p = 0; p < 32; ++p) {
    const int li = p * 256 + tid;
    const int f = li >> 6, nn = li & 63;
    const int u16 = nn & 15, gg = (nn >> 4) & 3;
    const int nsrc = gg * 1024 + ugrp * 16 + u16;
    sW[f][nn] = W[(size_t)f * N4 + nsrc];
  }
  __syncthreads();

  const int tx = tid & 15;
  const int ty = tid >> 4;
  float acc[4][4] = {};
  for (int f = 0; f < 128; ++f) {
    float a[4], b[4];
#pragma unroll
    for (int j = 0; j < 4; ++j) a[j] = sWd[tx * 4 + j][f];
#pragma unroll
    for (int i = 0; i < 4; ++i) b[i] = sW[f][ty * 4 + i];
#pragma unroll
    for (int i = 0; i < 4; ++i)
#pragma unroll
      for (int j = 0; j < 4; ++j) acc[i][j] += a[j] * b[i];
  }

#pragma unroll
  for (int i = 0; i < 4; ++i) {
    const int np = n0 + ty * 4 + i;
    const int u16 = np & 15, gg = (np >> 4) & 3;
    const int nsrc = gg * 1024 + ugrp * 16 + u16;
    const int cf = np >> 4;
#pragma unroll
    for (int j = 0; j < 4; ++j) {
      const int k = k0 + tx * 4 + j;
      const float v = rW[(size_t)k * N4 + nsrc] + acc[i][j];
      const int kc = k >> 5, lane = ((k >> 3) & 3) * 16 + (np & 15), e = k & 7;
      Wp2F[(((size_t)cf * 32 + kc) * 64 + lane) * 8 + e] = f2bf(v);
    }
  }
}

// ---------------- fused LSTM step ----------------
// 128x128 tile, 4 waves (64x64 subtile each), K_STEP=64, 2-deep pipeline:
// 3 LDS A-buffers + 3 B-register sets, counted vmcnt (24/12/0), raw barriers.
// KT: K length; NKS: WpF kc-stride; HASX: x-part present; ZC: c==0 (t=0).
template<int KT, int NKS, bool HASX, bool ZC>
__global__ __launch_bounds__(256, 2)
void lstm_step_kernel(const ushort* __restrict__ Xc,   // [B][128] bf16
                      const ushort* __restrict__ Hin,  // [B][1024] bf16
                      const ushort* __restrict__ WpF,  // fragment-ordered weights
                      const float* __restrict__ bias,  // [4096] fp32, orig gate order
                      float* __restrict__ CF,          // fragment-ordered c state
                      ushort* __restrict__ Hout) {     // [B][1024] bf16
  __shared__ alignas(16) ushort sA[3 * 8192];          // 3 bufs x [2 kk][128 r][32 k']

  const int bid = blockIdx.x;
  const int wg = (bid & 7) * 64 + (bid >> 3);   // bijective XCD chunk swizzle (512%8==0)
  const int bx = wg & 15, by = wg >> 4;
  const int bm = bx * 128;
  const int bnf = by * 8;                        // B col-frag base (128 cols = 8 frags)

  const int tid = threadIdx.x;
  const int wid = tid >> 6;
  const int l = tid & 63;
  const int wr = wid >> 1;     // 0..1: rows wr*64
  const int wc = wid & 1;      // 0..1: cols wc*64

  const int rloc = l >> 2;
  const int slot = l & 3;
  const int gsw = slot ^ ((rloc >> 1) & 3);
  const int l15 = l & 15;
  const int kg = l >> 4;
  const int nfbase = bnf + wc * 4;

  constexpr int NT = KT / 64;
  constexpr int S = NT - 2;       // steady iterations
  constexpr int G = S / 3;
  constexpr int R = S % 3;

  f32x4 acc[4][4] = {};
  bf16x8 bv0[2][4], bv1[2][4], bv2[2][4];

  // c-state prefetch (fragment-ordered: coalesced float4)
  const int Rr = bx * 2 + wr;           // 0..31
  const int U = by * 2 + wc;            // 0..63
  const size_t cfbase = (((size_t)Rr * 64 + U) * 64 + l) * 16;
  f32x4 cpre[4];
  if (!ZC) {
#pragma unroll
    for (int m = 0; m < 4; ++m)
      cpre[m] = *reinterpret_cast<const f32x4*>(CF + cfbase + m * 4);
  }

  auto STAGE_A = [&](int t, int buf) {
    const int bufofs = buf * 8192;
    const int k0base = t * 64;
#pragma unroll
    for (int q = 0; q < 4; ++q) {
      const int c = wid * 4 + q;          // 0..15
      const int r = (c & 7) * 16 + rloc;
      const int k0s = k0base + (c >> 3) * 32;
      const ushort* src;
      if (HASX && k0s < FEAT) src = Xc + (size_t)(bm + r) * FEAT + k0s + gsw * 8;
      else                    src = Hin + (size_t)(bm + r) * UNITS + (k0s - (HASX ? FEAT : 0)) + gsw * 8;
      gload_lds16(src, &sA[bufofs + c * 512]);
    }
  };

  auto LOADB = [&](int t, bf16x8 (&bv)[2][4]) {
#pragma unroll
    for (int kk = 0; kk < 2; ++kk)
#pragma unroll
      for (int n = 0; n < 4; ++n) {
        const size_t kc = (size_t)(t * 2 + kk);
        bv[kk][n] = *reinterpret_cast<const bf16x8*>(
            WpF + (((size_t)(nfbase + n) * NKS + kc) * 64 + l) * 8);
      }
  };

  auto COMPUTE = [&](bf16x8 (&bv)[2][4], int buf) {
    const int bufofs = buf * 8192;
    __builtin_amdgcn_s_setprio(1);
#pragma unroll
    for (int kk = 0; kk < 2; ++kk) {
      bf16x8 av[4];
#pragma unroll
      for (int m = 0; m < 4; ++m) {
        const int r = wr * 64 + m * 16 + l15;
        const int sph = kg ^ ((r >> 1) & 3);
        av[m] = *reinterpret_cast<const bf16x8*>(&sA[bufofs + kk * 4096 + r * 32 + sph * 8]);
      }
#pragma unroll
      for (int m = 0; m < 4; ++m)
#pragma unroll
        for (int n = 0; n < 4; ++n)
          acc[m][n] = __builtin_amdgcn_mfma_f32_16x16x32_bf16(av[m], bv[kk][n], acc[m][n], 0, 0, 0);
    }
    __builtin_amdgcn_s_setprio(0);
  };

  // mode: 0 = steady (prefetch t+2, wait 24), 1 = tail2 (wait 12), 2 = tail1 (wait 0)
  auto ITER = [&](int t, bf16x8 (&bvC)[2][4], bf16x8 (&bvL)[2][4],
                  int cb, int lb, int mode) {
    if (mode == 0) {
      STAGE_A(t + 2, lb);
      LOADB(t + 2, bvL);
    }
    __builtin_amdgcn_sched_barrier(0);
    if (mode == 0)      asm volatile("s_waitcnt vmcnt(24)" ::: "memory");
    else if (mode == 1) asm volatile("s_waitcnt vmcnt(12)" ::: "memory");
    else                asm volatile("s_waitcnt vmcnt(0)" ::: "memory");
    asm volatile("s_barrier" ::: "memory");
    COMPUTE(bvC, cb);
    asm volatile("s_barrier" ::: "memory");
  };

  // prologue: 2 iterations in flight
  STAGE_A(0, 0); LOADB(0, bv0);
  STAGE_A(1, 1); LOADB(1, bv1);

  int t = 0;
  for (int g = 0; g < G; ++g) {
    ITER(t, bv0, bv2, 0, 2, 0); ++t;
    ITER(t, bv1, bv0, 1, 0, 0); ++t;
    ITER(t, bv2, bv1, 2, 1, 0); ++t;
  }
  if constexpr (R == 0) {
    ITER(t, bv0, bv0, 0, 0, 1); ++t;
    ITER(t, bv1, bv1, 1, 1, 2); ++t;
  } else if constexpr (R == 1) {
    ITER(t, bv0, bv2, 0, 2, 0); ++t;
    ITER(t, bv1, bv1, 1, 1, 1); ++t;
    ITER(t, bv2, bv2, 2, 2, 2); ++t;
  } else {
    ITER(t, bv0, bv2, 0, 2, 0); ++t;
    ITER(t, bv1, bv0, 1, 0, 0); ++t;
    ITER(t, bv2, bv2, 2, 2, 1); ++t;
    ITER(t, bv0, bv0, 0, 0, 2); ++t;
  }

  // ---- epilogue: gates + state update ----
  const int unit = U * 16 + l15;
  const float bi = bias[unit];
  const float bf_ = bias[1024 + unit];
  const float bg = bias[2048 + unit];
  const float bo = bias[3072 + unit];

#pragma unroll
  for (int m = 0; m < 4; ++m) {
    const int rowb = bm + wr * 64 + m * 16 + kg * 4;
    f32x4 cout;
#pragma unroll
    for (int j = 0; j < 4; ++j) {
      const float i_ = sigm(acc[m][0][j] + bi);
      const float f_ = sigm(acc[m][1][j] + bf_);
      const float g_ = tanh_f(acc[m][2][j] + bg);
      const float o_ = sigm(acc[m][3][j] + bo);
      const float cn = ZC ? (i_ * g_) : (f_ * cpre[m][j] + i_ * g_);
      cout[j] = cn;
      Hout[(size_t)(rowb + j) * UNITS + unit] = f2bf(o_ * tanh_f(cn));
    }
    *reinterpret_cast<f32x4*>(CF + cfbase + m * 4) = cout;
  }
}

// ---------------- batched dense: out[b][s][f] = Hall[s][b] . Wd[:,f] + db[f] ----------------
__global__ __launch_bounds__(256)
void dense_all_kernel(const ushort* __restrict__ Hall,  // [24][2048][1024] bf16
                      const ushort* __restrict__ Wdt,   // [128][1024] bf16
                      const float* __restrict__ db,
                      float* __restrict__ out) {        // [2048][24][128] fp32
  __shared__ alignas(16) ushort sA[2][64 * 32];
  __shared__ alignas(16) ushort sB[2][128 * 32];

  const int bm = blockIdx.x * 64;
  const int tid = threadIdx.x;
  const int wid = tid >> 6;
  const int l = tid & 63;
  const int wr = wid >> 1;
  const int wc = wid & 1;

  const int rloc = l >> 2;
  const int slot = l & 3;
  const int gsw = slot ^ ((rloc >> 1) & 3);
  const int l15 = l & 15;
  const int kg = l >> 4;

  f32x4 acc[2][4] = {};

  auto STAGE = [&](int k0s, int bsel) {
#pragma unroll
    for (int q = 0; q < 3; ++q) {
      const int c = wid * 3 + q;   // 0..11: 0-3 sA, 4-11 sB
      if (c < 4) {
        const int r = c * 16 + rloc;
        gload_lds16(Hall + (size_t)(bm + r) * UNITS + k0s + gsw * 8, &sA[bsel][c * 512]);
      } else {
        const int cb = c - 4;
        const int r = cb * 16 + rloc;
        gload_lds16(Wdt + (size_t)r * UNITS + k0s + gsw * 8, &sB[bsel][cb * 512]);
      }
    }
  };

  STAGE(0, 0);
  __syncthreads();
  int cur = 0;
  for (int t = 0; t < 32; ++t) {
    if (t + 1 < 32) STAGE((t + 1) * 32, cur ^ 1);

    bf16x8 av[2], bv[4];
#pragma unroll
    for (int m = 0; m < 2; ++m) {
      const int r = wr * 32 + m * 16 + l15;
      const int sph = kg ^ ((r >> 1) & 3);
      av[m] = *reinterpret_cast<const bf16x8*>(&sA[cur][r * 32 + sph * 8]);
    }
#pragma unroll
    for (int n = 0; n < 4; ++n) {
      const int r = wc * 64 + n * 16 + l15;
      const int sph = kg ^ ((r >> 1) & 3);
      bv[n] = *reinterpret_cast<const bf16x8*>(&sB[cur][r * 32 + sph * 8]);
    }
#pragma unroll
    for (int m = 0; m < 2; ++m)
#pragma unroll
      for (int n = 0; n < 4; ++n)
        acc[m][n] = __builtin_amdgcn_mfma_f32_16x16x32_bf16(av[m], bv[n], acc[m][n], 0, 0, 0);

    __syncthreads();
    cur ^= 1;
  }

#pragma unroll
  for (int n = 0; n < 4; ++n) {
    const int f = wc * 64 + n * 16 + l15;
    const float bb = db[f];
#pragma unroll
    for (int m = 0; m < 2; ++m) {
#pragma unroll
      for (int j = 0; j < 4; ++j) {
        const int r = bm + wr * 32 + m * 16 + kg * 4 + j;
        const int s = r >> 11, b = r & 2047;
        out[((size_t)b * OUT_STEPS + s) * FEAT + f] = acc[m][n][j] + bb;
      }
    }
  }
}

// ---------------- launch ----------------
extern "C" void kernel_launch(void* const* d_in, const int* in_sizes, int n_in,
                              void* d_out, int out_size, void* d_ws, size_t ws_size,
                              hipStream_t stream) {
  const float* inputs  = (const float*)d_in[0];
  const float* kernelW = (const float*)d_in[1];
  const float* recW    = (const float*)d_in[2];
  const float* bias    = (const float*)d_in[3];
  const float* dw      = (const float*)d_in[4];
  const float* db      = (const float*)d_in[5];
  float* out = (float*)d_out;

  char* ws = (char*)d_ws;
  float*  CF   = (float*)ws;                                   // 8 MB (fragment-ordered c)
  ushort* Xb   = (ushort*)(ws + 8388608);                      // 24 MB (warmup only)
  ushort* Wp2F = Xb;                                           // 8 MB, aliases Xb
  ushort* Hb0  = (ushort*)(ws + 33554432);                     // 4 MB
  ushort* Hb1  = (ushort*)(ws + 37748736);                     // 4 MB
  ushort* WpF  = (ushort*)(ws + 41943040);                     // 9 MB
  ushort* Wdt  = (ushort*)(ws + 51380224);                     // 256 KB
  float*  b2   = (float*)(ws + 51642368);                      // 16 KB
  ushort* Hall = (ushort*)(ws + 51658752);                     // 96 MB: [24][2048][1024]
  ushort* Hb[2] = {Hb0, Hb1};
  const size_t HSLOT = (size_t)BATCH * UNITS;

  convert_inputs_kernel<<<TSEQ * BATCH * FEAT / 1024, 256, 0, stream>>>(inputs, Xb);
  prep_wF_kernel<<<(N4 / 16) * 36 * 64 / 256, 256, 0, stream>>>(kernelW, recW, WpF);
  prep_wd_kernel<<<FEAT * UNITS / 256, 256, 0, stream>>>(dw, Wdt);
  prep_b2_kernel<<<N4 / 256, 256, 0, stream>>>(bias, db, kernelW, b2);

  // t = 0: c = h = 0 -> K=128 (x only), no C read, no memsets needed.
  lstm_step_kernel<128, 36, true, true><<<512, 256, 0, stream>>>(
      Xb, Hb0 /*unused*/, WpF, bias, CF, Hb1);
  int cur = 1;
  for (int t = 1; t < TSEQ; ++t) {
    ushort* hout = (t == TSEQ - 1) ? Hall : Hb[cur ^ 1];
    lstm_step_kernel<KTOT, 36, true, false><<<512, 256, 0, stream>>>(
        Xb + (size_t)t * BATCH * FEAT, Hb[cur], WpF, bias, CF, hout);
    cur ^= 1;
  }
  // Wp2F aliases Xb — build only after warmup consumed Xb.
  prep_u_kernel<<<dim3(64, 16), 256, 0, stream>>>(dw, kernelW, recW, Wp2F);

  for (int s = 1; s < OUT_STEPS; ++s) {
    lstm_step_kernel<UNITS, 32, false, false><<<512, 256, 0, stream>>>(
        nullptr, Hall + (size_t)(s - 1) * HSLOT, Wp2F, b2, CF, Hall + (size_t)s * HSLOT);
  }
  dense_all_kernel<<<(OUT_STEPS * BATCH) / 64, 256, 0, stream>>>(Hall, Wdt, db, out);
}